// Round 5
// baseline (1140.741 us; speedup 1.0000x reference)
//
#include <hip/hip_runtime.h>

// Transformer block: B=64, T=320, E=1024, H=16, HS=64
// Round 4: gemm_mfma staging via __builtin_amdgcn_global_load_lds (width=16,
// linear LDS dest + pre-swizzled global source) + XCD-chunked block swizzle.
// Attention / LN / tcast unchanged (validated: absmax 0.031).

#define B_ 64
#define T_ 320
#define E_ 1024
#define H_ 16
#define HS_ 64
#define NTOK (B_ * T_)   // 20480

typedef __attribute__((ext_vector_type(8))) __bf16 bf16x8;
typedef __attribute__((ext_vector_type(4))) float f32x4;

__device__ __forceinline__ unsigned short f2bf(float f) {
    unsigned u = __builtin_bit_cast(unsigned, f);
    u += 0x7fffu + ((u >> 16) & 1u);          // round-to-nearest-even
    return (unsigned short)(u >> 16);
}
__device__ __forceinline__ float bf2f(unsigned short b) {
    return __builtin_bit_cast(float, (unsigned)b << 16);
}
// async global->LDS, 16B per lane; lds dest must be wave-uniform base (HW adds lane*16)
__device__ __forceinline__ void gload16(const void* g, void* l) {
    __builtin_amdgcn_global_load_lds(
        (const __attribute__((address_space(1))) unsigned int*)g,
        (__attribute__((address_space(3))) unsigned int*)l, 16, 0, 0);
}

// ------------------------------------------------------------ LayerNorm -> bf16
__global__ __launch_bounds__(256) void ln_kernel(const float* __restrict__ x,
                                                 const float* __restrict__ w,
                                                 const float* __restrict__ b,
                                                 unsigned short* __restrict__ y) {
    int row = blockIdx.x;
    int t = threadIdx.x;
    const float4* xr = (const float4*)(x + (size_t)row * E_);
    float4 v = xr[t];
    float s = v.x + v.y + v.z + v.w;
    float s2 = v.x * v.x + v.y * v.y + v.z * v.z + v.w * v.w;
#pragma unroll
    for (int o = 1; o < 64; o <<= 1) {
        s += __shfl_xor(s, o);
        s2 += __shfl_xor(s2, o);
    }
    __shared__ float rs[4], rs2[4];
    int wv = t >> 6;
    if ((t & 63) == 0) { rs[wv] = s; rs2[wv] = s2; }
    __syncthreads();
    s = rs[0] + rs[1] + rs[2] + rs[3];
    s2 = rs2[0] + rs2[1] + rs2[2] + rs2[3];
    float mu = s * (1.0f / E_);
    float var = s2 * (1.0f / E_) - mu * mu;
    float inv = rsqrtf(var + 1e-5f);
    float4 w4 = ((const float4*)w)[t];
    float4 b4 = ((const float4*)b)[t];
    ushort4 o4;
    o4.x = f2bf((v.x - mu) * inv * w4.x + b4.x);
    o4.y = f2bf((v.y - mu) * inv * w4.y + b4.y);
    o4.z = f2bf((v.z - mu) * inv * w4.z + b4.z);
    o4.w = f2bf((v.w - mu) * inv * w4.w + b4.w);
    *(ushort4*)(y + (size_t)row * E_ + 4 * t) = o4;
}

// ------------------------------------------------- transpose-cast fp32->bf16
__global__ __launch_bounds__(256) void tcast_kernel(const float* __restrict__ src,
                                                    unsigned short* __restrict__ dst,
                                                    int K, int N, long sStride, long dStride) {
    src += (size_t)blockIdx.z * sStride;
    dst += (size_t)blockIdx.z * dStride;
    __shared__ float tile[64][65];
    int k0 = blockIdx.y * 64, n0 = blockIdx.x * 64;
    int tx = threadIdx.x & 63, ty = threadIdx.x >> 6;
#pragma unroll
    for (int r = ty; r < 64; r += 4)
        tile[r][tx] = src[(size_t)(k0 + r) * N + n0 + tx];
    __syncthreads();
#pragma unroll
    for (int r = ty; r < 64; r += 4)
        dst[(size_t)(n0 + r) * K + k0 + tx] = f2bf(tile[tx][r]);
}

// ------------------------------------------------------------- MFMA GEMM
// C[M,N] = epilogue( A[M,K]bf16 @ Bt[N,K]bf16^T ). 128x128 tile, BK=32,
// 4 waves (2x2), each wave 64x64 = 4x4 frags of 16x16x32.
// Staging: global_load_lds width=16; LDS linear, XOR swizzle applied on the
// GLOBAL source slot (involution) so reads use slot ^ ((row>>1)&3).
// Block ids XCD-chunk swizzled (grid total % 8 == 0 for all call sites).
template <bool BF16OUT, bool BIAS, bool RELU, bool RESID>
__global__ __launch_bounds__(256)
void gemm_mfma(const unsigned short* __restrict__ A,   // [M][K] bf16
               const unsigned short* __restrict__ Bt,  // [N][K] bf16
               const float* __restrict__ bias,         // [N] fp32
               const float* __restrict__ resid,        // [M][N] fp32
               void* __restrict__ Cout, int K, int N) {
    __shared__ uint4 A4[128 * 4];
    __shared__ uint4 B4[128 * 4];
    // XCD-chunked bijective swizzle: flat%8 (the XCD) -> contiguous chunk
    const int total = gridDim.x * gridDim.y;
    const int flat = blockIdx.y * gridDim.x + blockIdx.x;
    const int cpx = total >> 3;
    const int swz = (flat & 7) * cpx + (flat >> 3);
    const int m0 = (swz / gridDim.x) * 128;
    const int n0 = (swz % gridDim.x) * 128;

    const int tid = threadIdx.x;
    const int lane = tid & 63;
    const int wave = tid >> 6;
    const int wr = wave >> 1, wc = wave & 1;
    const int r16 = lane & 15;
    const int s = lane >> 4;
    const int sw = s ^ ((r16 >> 1) & 3);

    // staging geometry: wave covers rows [wave*32, wave*32+32) of A and B,
    // two 1KB instructions each (16 rows x 4 slots x 16B).
    const int rin = lane >> 2;                 // row within 16-row group
    const int sl = lane & 3;                   // lds slot (linear)
    const int gsl = sl ^ ((rin >> 1) & 3);     // global slot (pre-swizzled src)
    const int rowA = wave * 32 + rin;
    const unsigned short* Ag0 = A + (size_t)(m0 + rowA) * K + gsl * 8;
    const unsigned short* Ag1 = Ag0 + (size_t)16 * K;
    const unsigned short* Bg0 = Bt + (size_t)(n0 + rowA) * K + gsl * 8;
    const unsigned short* Bg1 = Bg0 + (size_t)16 * K;
    uint4* ldsA0 = &A4[(wave * 32) * 4];
    uint4* ldsA1 = &A4[(wave * 32 + 16) * 4];
    uint4* ldsB0 = &B4[(wave * 32) * 4];
    uint4* ldsB1 = &B4[(wave * 32 + 16) * 4];

    f32x4 acc[4][4];
#pragma unroll
    for (int i = 0; i < 4; i++)
#pragma unroll
        for (int j = 0; j < 4; j++) acc[i][j] = (f32x4){0.f, 0.f, 0.f, 0.f};

    const bf16x8* Ab = (const bf16x8*)A4;
    const bf16x8* Bb = (const bf16x8*)B4;

    for (int k0 = 0; k0 < K; k0 += 32) {
        __syncthreads();                 // previous-iter readers done
        gload16(Ag0 + k0, ldsA0);
        gload16(Ag1 + k0, ldsA1);
        gload16(Bg0 + k0, ldsB0);
        gload16(Bg1 + k0, ldsB1);
        __syncthreads();                 // vmcnt(0) drain -> tile visible
        bf16x8 af[4], bf[4];
#pragma unroll
        for (int i = 0; i < 4; i++) {
            af[i] = Ab[(((wr << 6) + (i << 4) + r16) << 2) + sw];
            bf[i] = Bb[(((wc << 6) + (i << 4) + r16) << 2) + sw];
        }
#pragma unroll
        for (int i = 0; i < 4; i++)
#pragma unroll
            for (int j = 0; j < 4; j++)
                acc[i][j] = __builtin_amdgcn_mfma_f32_16x16x32_bf16(af[i], bf[j], acc[i][j], 0, 0, 0);
    }

    const int crow0 = m0 + wr * 64;
    const int ccol0 = n0 + wc * 64;
#pragma unroll
    for (int j = 0; j < 4; j++) {
        int gcol = ccol0 + j * 16 + r16;
        float bv = BIAS ? bias[gcol] : 0.f;
#pragma unroll
        for (int i = 0; i < 4; i++) {
            int growb = crow0 + i * 16 + s * 4;
#pragma unroll
            for (int r = 0; r < 4; r++) {
                float vo = acc[i][j][r] + bv;
                if (RELU) vo = fmaxf(vo, 0.f);
                int grow = growb + r;
                if (RESID) vo += resid[(size_t)grow * N + gcol];
                if (BF16OUT)
                    ((unsigned short*)Cout)[(size_t)grow * N + gcol] = f2bf(vo);
                else
                    ((float*)Cout)[(size_t)grow * N + gcol] = vo;
            }
        }
    }
}

// ------------------------------------------------------------- MFMA Flash attn
// (unchanged, validated round 3)
__global__ __launch_bounds__(256) void attn_mfma(const unsigned short* __restrict__ qkv,
                                                 unsigned short* __restrict__ attn) {
    const int it = blockIdx.x;
    const int bh = blockIdx.y;
    const int b = bh >> 4, head = bh & 15;
    __shared__ uint4 KsV[512];          // K tile  [kv=64][d=64] bf16, swizzled
    __shared__ uint4 VtV[512];          // V^T tile [d=64][kv=64] bf16, swizzled
    __shared__ uint4 PsV[4][128];       // per-wave P [q=16][kv=64] bf16, swizzled
    unsigned short* Ks = (unsigned short*)KsV;
    unsigned short* Vt = (unsigned short*)VtV;

    const int tid = threadIdx.x;
    const int lane = tid & 63;
    const int w = tid >> 6;
    const int r16 = lane & 15;
    const int s = lane >> 4;
    unsigned short* P = (unsigned short*)PsV[w];

    const int qg = it * 64 + w * 16 + r16;
    const size_t qrow = (size_t)(b * T_ + qg) * 3072;

    bf16x8 qf0 = *(const bf16x8*)(qkv + qrow + head * 64 + 0 * 32 + s * 8);
    bf16x8 qf1 = *(const bf16x8*)(qkv + qrow + head * 64 + 1 * 32 + s * 8);

    f32x4 accO[4];
#pragma unroll
    for (int i = 0; i < 4; i++) accO[i] = (f32x4){0.f, 0.f, 0.f, 0.f};
    float m = -1e30f, l = 0.f;

    for (int j = 0; j <= it; j++) {
        __syncthreads();
#pragma unroll
        for (int half = 0; half < 2; half++) {
            int cid = tid + half * 256;
            int row = cid >> 3, sl = cid & 7;
            size_t tok = (size_t)(b * T_ + j * 64 + row) * 3072 + head * 64 + sl * 8;
            uint4 kc = *(const uint4*)(qkv + tok + 1024);
            uint4 vc = *(const uint4*)(qkv + tok + 2048);
            *(uint4*)(Ks + row * 64 + ((sl ^ (row & 7)) * 8)) = kc;
            union { uint4 u; unsigned short h[8]; } vv; vv.u = vc;
#pragma unroll
            for (int e = 0; e < 8; e++) {
                int d = sl * 8 + e;
                Vt[d * 64 + (((row >> 3) ^ (d & 7)) * 8) + (row & 7)] = vv.h[e];
            }
        }
        __syncthreads();

        f32x4 accS[4];
#pragma unroll
        for (int i = 0; i < 4; i++) accS[i] = (f32x4){0.f, 0.f, 0.f, 0.f};
#pragma unroll
        for (int c = 0; c < 2; c++) {
            bf16x8 qc = c ? qf1 : qf0;
#pragma unroll
            for (int i = 0; i < 4; i++) {
                int kvr = i * 16 + r16;
                bf16x8 kf = *(const bf16x8*)(Ks + kvr * 64 + (((c * 4 + s) ^ (kvr & 7)) * 8));
                accS[i] = __builtin_amdgcn_mfma_f32_16x16x32_bf16(kf, qc, accS[i], 0, 0, 0);
            }
        }

        float sv[16];
        float smax = -1e30f;
#pragma unroll
        for (int i = 0; i < 4; i++)
#pragma unroll
            for (int r = 0; r < 4; r++) {
                float vsc = accS[i][r] * 0.03125f;
                int kvg = j * 64 + i * 16 + 4 * s + r;
                if (kvg > qg) vsc = -1e30f;
                sv[i * 4 + r] = vsc;
                smax = fmaxf(smax, vsc);
            }
        smax = fmaxf(smax, __shfl_xor(smax, 16));
        smax = fmaxf(smax, __shfl_xor(smax, 32));
        float mn = fmaxf(m, smax);
        float al = __expf(m - mn);
        float ps = 0.f;
        unsigned short pb[16];
#pragma unroll
        for (int idx = 0; idx < 16; idx++) {
            float p = __expf(sv[idx] - mn);
            ps += p;
            pb[idx] = f2bf(p);
        }
        ps += __shfl_xor(ps, 16);
        ps += __shfl_xor(ps, 32);
        l = l * al + ps;
        m = mn;
#pragma unroll
        for (int i = 0; i < 4; i++)
#pragma unroll
            for (int r = 0; r < 4; r++) accO[i][r] *= al;

#pragma unroll
        for (int i = 0; i < 4; i++)
#pragma unroll
            for (int r = 0; r < 4; r++) {
                int kv = i * 16 + 4 * s + r;
                P[r16 * 64 + (((kv >> 3) ^ (r16 & 7)) * 8) + (kv & 7)] = pb[i * 4 + r];
            }
        asm volatile("s_waitcnt lgkmcnt(0)" ::: "memory");

#pragma unroll
        for (int c = 0; c < 2; c++) {
            bf16x8 pf = *(const bf16x8*)(P + r16 * 64 + (((c * 4 + s) ^ (r16 & 7)) * 8));
#pragma unroll
            for (int i = 0; i < 4; i++) {
                int d = i * 16 + r16;
                bf16x8 vf = *(const bf16x8*)(Vt + d * 64 + (((c * 4 + s) ^ (d & 7)) * 8));
                accO[i] = __builtin_amdgcn_mfma_f32_16x16x32_bf16(vf, pf, accO[i], 0, 0, 0);
            }
        }
    }

    float inv = 1.0f / l;
#pragma unroll
    for (int i = 0; i < 4; i++)
#pragma unroll
        for (int r = 0; r < 4; r++) {
            int d = i * 16 + 4 * s + r;
            P[r16 * 64 + (((d >> 3) ^ (r16 & 7)) * 8) + (d & 7)] = f2bf(accO[i][r] * inv);
        }
    asm volatile("s_waitcnt lgkmcnt(0)" ::: "memory");
#pragma unroll
    for (int half = 0; half < 2; half++) {
        int cid = lane + half * 64;
        int row = cid >> 3, sl = cid & 7;
        uint4 o = *(const uint4*)(P + row * 64 + ((sl ^ (row & 7)) * 8));
        *(uint4*)(attn + (size_t)(b * T_ + it * 64 + w * 16 + row) * E_ + head * 64 + sl * 8) = o;
    }
}

// ---------------------------------------------------------------- launch
extern "C" void kernel_launch(void* const* d_in, const int* in_sizes, int n_in,
                              void* d_out, int out_size, void* d_ws, size_t ws_size,
                              hipStream_t stream) {
    const float* x    = (const float*)d_in[0];
    const float* Wq   = (const float*)d_in[1];
    const float* Wk   = (const float*)d_in[2];
    const float* Wv   = (const float*)d_in[3];
    const float* Wo   = (const float*)d_in[4];
    const float* bo   = (const float*)d_in[5];
    const float* W1   = (const float*)d_in[6];
    const float* b1   = (const float*)d_in[7];
    const float* W2   = (const float*)d_in[8];
    const float* b2   = (const float*)d_in[9];
    const float* ln1w = (const float*)d_in[10];
    const float* ln1b = (const float*)d_in[11];
    const float* ln2w = (const float*)d_in[12];
    const float* ln2b = (const float*)d_in[13];
    float* out = (float*)d_out;

    unsigned short* ws = (unsigned short*)d_ws;
    unsigned short* qkvWt = ws;                        //  [3072][1024]
    unsigned short* WoT   = qkvWt + 3072 * 1024;       //  [1024][1024]
    unsigned short* W1T   = WoT + 1024 * 1024;         //  [4096][1024]
    unsigned short* W2T   = W1T + 4096 * 1024;         //  [1024][4096]
    unsigned short* hbuf  = W2T + 1024 * 4096;         //  [20480][1024]
    unsigned short* qkv   = hbuf + (size_t)NTOK * E_;  //  [20480][3072]
    unsigned short* abuf  = qkv + (size_t)NTOK * 3 * E_; // [20480][1024]
    unsigned short* inter = qkv;                       //  [20480][4096] overlays qkv+abuf

    tcast_kernel<<<dim3(1, 16, 16), 256, 0, stream>>>(Wq, qkvWt, E_, HS_,
                                                      (long)E_ * HS_, (long)HS_ * E_);
    tcast_kernel<<<dim3(1, 16, 16), 256, 0, stream>>>(Wk, qkvWt + 1024 * 1024, E_, HS_,
                                                      (long)E_ * HS_, (long)HS_ * E_);
    tcast_kernel<<<dim3(1, 16, 16), 256, 0, stream>>>(Wv, qkvWt + 2048 * 1024, E_, HS_,
                                                      (long)E_ * HS_, (long)HS_ * E_);
    tcast_kernel<<<dim3(16, 16, 1), 256, 0, stream>>>(Wo, WoT, E_, E_, 0, 0);
    tcast_kernel<<<dim3(64, 16, 1), 256, 0, stream>>>(W1, W1T, E_, 4 * E_, 0, 0);
    tcast_kernel<<<dim3(16, 64, 1), 256, 0, stream>>>(W2, W2T, 4 * E_, E_, 0, 0);

    // 1) h = LN1(x) -> bf16
    ln_kernel<<<NTOK, 256, 0, stream>>>(x, ln1w, ln1b, hbuf);
    // 2) qkv = h @ [Wq|Wk|Wv]   grid 24*160 = 3840 (%8==0)
    gemm_mfma<true, false, false, false><<<dim3(24, 160), 256, 0, stream>>>(
        hbuf, qkvWt, nullptr, nullptr, qkv, 1024, 3072);
    // 3) attention (MFMA) -> bf16 (B,T,E)
    attn_mfma<<<dim3(T_ / 64, B_ * H_), 256, 0, stream>>>(qkv, abuf);
    // 4) x1 = x + attn @ Wo + bo -> fp32 d_out   grid 1280 (%8==0)
    gemm_mfma<false, true, false, true><<<dim3(8, 160), 256, 0, stream>>>(
        abuf, WoT, bo, x, out, 1024, 1024);
    // 5) h2 = LN2(x1) -> bf16
    ln_kernel<<<NTOK, 256, 0, stream>>>(out, ln2w, ln2b, hbuf);
    // 6) inter = relu(h2 @ W1 + b1) -> bf16   grid 5120 (%8==0)
    gemm_mfma<true, true, true, false><<<dim3(32, 160), 256, 0, stream>>>(
        hbuf, W1T, b1, nullptr, inter, 1024, 4096);
    // 7) out = x1 + inter @ W2 + b2 -> fp32 d_out   grid 1280 (%8==0)
    gemm_mfma<false, true, false, true><<<dim3(8, 160), 256, 0, stream>>>(
        inter, W2T, b2, out, out, 4096, 1024);
}